// Round 7
// baseline (206.054 us; speedup 1.0000x reference)
//
#include <hip/hip_runtime.h>

#define CH 256

// DPP helper: v += dpp_move(v); bound_ctrl=true => out-of-range lanes read 0.
template <int CTRL>
__device__ __forceinline__ float dppAdd(float v) {
    const int m = __builtin_amdgcn_update_dpp(0, __builtin_bit_cast(int, v), CTRL, 0xf, 0xf, true);
    return v + __builtin_bit_cast(float, m);
}

// ---------------- embed + fc_input (dual-branch): 16 rows/block
__global__ __launch_bounds__(256) void embed_fc_kernel(
    const int* __restrict__ x,
    const float* __restrict__ e0a, const float* __restrict__ e1a, const float* __restrict__ e2a,
    const float* __restrict__ Wina, const float* __restrict__ bina, float* __restrict__ h0a,
    const float* __restrict__ e0b, const float* __restrict__ e1b, const float* __restrict__ e2b,
    const float* __restrict__ Winb, const float* __restrict__ binb, float* __restrict__ h0b,
    const int blocksPer)
{
    __shared__ float sE[16][128];
    int bid = blockIdx.x;
    const float *e0, *e1, *e2, *Win, *bin;
    float* h0;
    if (bid < blocksPer) { e0 = e0a; e1 = e1a; e2 = e2a; Win = Wina; bin = bina; h0 = h0a; }
    else { bid -= blocksPer; e0 = e0b; e1 = e1b; e2 = e2b; Win = Winb; bin = binb; h0 = h0b; }

    const int row0 = bid * 16;
    const int t = threadIdx.x;
    for (int i = t; i < 16 * 128; i += 256) {
        const int r = i >> 7, k = i & 127;
        const int row = row0 + r;
        float v;
        if (k < 64)      v = e0[x[row * 3 + 0] * 64 + k];
        else if (k < 96) v = e1[x[row * 3 + 1] * 32 + (k - 64)];
        else             v = e2[x[row * 3 + 2] * 32 + (k - 96)];
        sE[r][k] = v;
    }
    __syncthreads();
    const int j = t;
    float acc[16];
    const float b = bin[j];
#pragma unroll
    for (int r = 0; r < 16; ++r) acc[r] = b;
    for (int k = 0; k < 128; ++k) {
        const float wv = Win[k * 256 + j];
#pragma unroll
        for (int r = 0; r < 16; ++r) acc[r] += sE[r][k] * wv;
    }
#pragma unroll
    for (int r = 0; r < 16; ++r) h0[(size_t)(row0 + r) * 256 + j] = acc[r];
}

// ---------------- co-attention aggregation (dual-branch); ONE WAVE per dst node
// L[k][m]=<D[k],Q[m]>; AC=row-softmax; AS[c][m]=softmax_m L[m][c]
// sum_k h[k] = [ sum Q | sum_m w_m D_m | sum_j u_j Q_j ], w=colsum(AS), u=AC^T w
// 4 waves/block, no __syncthreads: per-wave LDS slices, intra-wave RAW ordered
// by program order + compiler lgkmcnt. D,Q live in registers (float4/lane).
// launch_bounds(256,2): 256-VGPR budget so d[K]/q[K] stay RESIDENT (round-6's
// (256,4) made the allocator re-load fragments from global inside the L-phase;
// VGPR_Count=60 < the 80 needed for d+q was the tell).
template <int K>
__global__ __launch_bounds__(256, 2) void coagg_kernel(
    const float* __restrict__ fa, const int* __restrict__ iDa, const int* __restrict__ iQa,
    float* __restrict__ oa,
    const float* __restrict__ fb, const int* __restrict__ iDb, const int* __restrict__ iQb,
    float* __restrict__ ob,
    const int nPer, const int relu)
{
    __shared__ float sL[4][K][K];
    __shared__ float sLT[4][K][K];          // transposed copy for the merged softmax pass
    __shared__ float sAC[4][K][K];
    __shared__ float sAS[4][K][K];
    __shared__ float sw_[4][K], su_[4][K];
    __shared__ __align__(16) float sHsum[4][768];

    const int t = threadIdx.x;
    const int wv = t >> 6, lane = t & 63;
    int n = blockIdx.x * 4 + wv;             // grid sized so 4 | total nodes

    const float* feat; const int* idxD; const int* idxQ; float* outp;
    if (n < nPer) { feat = fa; idxD = iDa; idxQ = iQa; outp = oa; }
    else { n -= nPer; feat = fb; idxD = iDb; idxQ = iQb; outp = ob; }

    const float4* fp = (const float4*)feat;

    // gather D,Q rows into registers (lane owns float4 feature slice)
    float4 d[K], q[K];
#pragma unroll
    for (int k = 0; k < K; ++k) {
        const int rD = idxD[n * K + k];
        const int rQ = idxQ[n * K + k];
        d[k] = fp[(size_t)rD * 64 + lane];
        q[k] = fp[(size_t)rQ * 64 + lane];
    }
    const float4 resid = fp[(size_t)n * 64 + lane];

    // L-phase: verified 2-pair permlane32_swap + DPP ladder (round 5).
    //   lane31 -> dot(m0), lane63 -> dot(m0+1); store L and L^T.
#pragma unroll
    for (int k = 0; k < K; ++k) {
        const float4 dd = d[k];
#pragma unroll
        for (int m0 = 0; m0 < K; m0 += 2) {
            const float4 q0 = q[m0];
            float s0 = dd.x * q0.x + dd.y * q0.y + dd.z * q0.z + dd.w * q0.w;
            float s1 = 0.f;
            if (m0 + 1 < K) {                 // compile-time after unroll
                const float4 q1 = q[m0 + 1];
                s1 = dd.x * q1.x + dd.y * q1.y + dd.z * q1.z + dd.w * q1.w;
            }
            asm volatile("v_permlane32_swap_b32 %0, %1" : "+v"(s0), "+v"(s1));
            float r = s0 + s1;
            r = dppAdd<0x111>(r);   // row_shr:1
            r = dppAdd<0x112>(r);   // row_shr:2
            r = dppAdd<0x114>(r);   // row_shr:4
            r = dppAdd<0x118>(r);   // row_shr:8
            r = dppAdd<0x142>(r);   // row_bcast:15
            if (lane == 31) { sL[wv][k][m0] = r; sLT[wv][m0][k] = r; }
            if (lane == 63 && m0 + 1 < K) { sL[wv][k][m0 + 1] = r; sLT[wv][m0 + 1][k] = r; }
        }
    }

    // stage A: both softmaxes in ONE exec pass.
    //   lanes 0..K-1   : AC row r from sL[r][:]   -> sAC[r][:]
    //   lanes 16..16+K-1: AS row r from sLT[r][:] -> sAS[r][:]
    {
        const int g = lane >> 4;              // group 0 = AC, 1 = AS
        const int r2 = lane & 15;
        if (g < 2 && r2 < K) {
            const float* Lrow = (g == 0) ? &sL[wv][r2][0] : &sLT[wv][r2][0];
            float* Arow       = (g == 0) ? &sAC[wv][r2][0] : &sAS[wv][r2][0];
            float e_[K], mx = -1e30f;
#pragma unroll
            for (int m = 0; m < K; ++m) mx = fmaxf(mx, Lrow[m]);
            float ssum = 0.f;
#pragma unroll
            for (int m = 0; m < K; ++m) { e_[m] = __expf(Lrow[m] - mx); ssum += e_[m]; }
            const float inv = 1.f / ssum;
#pragma unroll
            for (int m = 0; m < K; ++m) Arow[m] = e_[m] * inv;
        }
    }
    // stage B: w[m] = colsum(AS)   (lanes 32..32+K-1; reads stage-A writes)
    {
        const int m2 = lane - 32;
        if (m2 >= 0 && m2 < K) {
            float s = 0.f;
#pragma unroll
            for (int k2 = 0; k2 < K; ++k2) s += sAS[wv][k2][m2];
            sw_[wv][m2] = s;
        }
    }
    // stage C: u[j] = sum_m w[m]*AC[m][j]   (lanes 48..48+K-1)
    {
        const int j2 = lane - 48;
        if (j2 >= 0 && j2 < K) {
            float s = 0.f;
#pragma unroll
            for (int m = 0; m < K; ++m) s += sw_[wv][m] * sAC[wv][m][j2];
            su_[wv][j2] = s;
        }
    }

    // stage D: weighted row sums (all lanes; D,Q in regs; w,u broadcast reads)
    float4 h0v = make_float4(0.f, 0.f, 0.f, 0.f);
    float4 h1v = make_float4(0.f, 0.f, 0.f, 0.f);
    float4 h2v = make_float4(0.f, 0.f, 0.f, 0.f);
#pragma unroll
    for (int kx = 0; kx < K; ++kx) {
        const float wk = sw_[wv][kx];
        const float uk = su_[wv][kx];
        const float4 qq = q[kx];
        const float4 dd = d[kx];
        h0v.x += qq.x;      h0v.y += qq.y;      h0v.z += qq.z;      h0v.w += qq.w;
        h1v.x += wk * dd.x; h1v.y += wk * dd.y; h1v.z += wk * dd.z; h1v.w += wk * dd.w;
        h2v.x += uk * qq.x; h2v.y += uk * qq.y; h2v.z += uk * qq.z; h2v.w += uk * qq.w;
    }
    ((float4*)&sHsum[wv][0])[lane]       = h0v;
    ((float4*)&sHsum[wv][0])[64 + lane]  = h1v;
    ((float4*)&sHsum[wv][0])[128 + lane] = h2v;

    // stage E: pool3 + mean_k + residual (reads same-wave sHsum)
    float ov[4];
#pragma unroll
    for (int i = 0; i < 4; ++i) {
        const int f = lane * 4 + i;
        ov[i] = (sHsum[wv][3 * f] + sHsum[wv][3 * f + 1] + sHsum[wv][3 * f + 2])
                * (1.0f / (3.0f * K));
    }
    float4 o = make_float4(resid.x + ov[0], resid.y + ov[1],
                           resid.z + ov[2], resid.w + ov[3]);
    if (relu) {
        o.x = fmaxf(o.x, 0.f); o.y = fmaxf(o.y, 0.f);
        o.z = fmaxf(o.z, 0.f); o.w = fmaxf(o.w, 0.f);
    }
    ((float4*)outp)[(size_t)n * 64 + lane] = o;
}

// ---------------- h2[.x256] @ Wout[256x128] + bout (dual-branch)
__global__ __launch_bounds__(128) void fc_out_kernel(
    const float* __restrict__ h2a, const float* __restrict__ Wouta,
    const float* __restrict__ bouta, float* __restrict__ oa,
    const float* __restrict__ h2b, const float* __restrict__ Woutb,
    const float* __restrict__ boutb, float* __restrict__ ob,
    const int blocksPer)
{
    __shared__ float sIn[8][256];
    int bid = blockIdx.x;
    const float *h2, *Wout, *bout; float* outp;
    if (bid < blocksPer) { h2 = h2a; Wout = Wouta; bout = bouta; outp = oa; }
    else { bid -= blocksPer; h2 = h2b; Wout = Woutb; bout = boutb; outp = ob; }

    const int row0 = bid * 8;
    const int t = threadIdx.x;
    for (int i = t; i < 8 * 256; i += 128) sIn[i >> 8][i & 255] = h2[(size_t)row0 * 256 + i];
    __syncthreads();
    float acc[8];
    const float b = bout[t];
#pragma unroll
    for (int r = 0; r < 8; ++r) acc[r] = b;
    for (int k = 0; k < 256; ++k) {
        const float wv = Wout[k * 128 + t];
#pragma unroll
        for (int r = 0; r < 8; ++r) acc[r] += sIn[r][k] * wv;
    }
#pragma unroll
    for (int r = 0; r < 8; ++r) outp[(size_t)(row0 + r) * 128 + t] = acc[r];
}

// ---------------- out = in[.x128] @ W[128x128] (dual)
__global__ __launch_bounds__(128) void mm128_kernel(
    const float* __restrict__ ina, const float* __restrict__ Wa, float* __restrict__ oa,
    const float* __restrict__ inb, const float* __restrict__ Wb, float* __restrict__ ob,
    const int blocksPer)
{
    __shared__ float sIn[8][128];
    int bid = blockIdx.x;
    const float *inp, *W; float* outp;
    if (bid < blocksPer) { inp = ina; W = Wa; outp = oa; }
    else { bid -= blocksPer; inp = inb; W = Wb; outp = ob; }

    const int row0 = bid * 8;
    const int t = threadIdx.x;
    for (int i = t; i < 8 * 128; i += 128) sIn[i >> 7][i & 127] = inp[(size_t)row0 * 128 + i];
    __syncthreads();
    float acc[8];
#pragma unroll
    for (int r = 0; r < 8; ++r) acc[r] = 0.f;
    for (int k = 0; k < 128; ++k) {
        const float wv = W[k * 128 + t];
#pragma unroll
        for (int r = 0; r < 8; ++r) acc[r] += sIn[r][k] * wv;
    }
#pragma unroll
    for (int r = 0; r < 8; ++r) outp[(size_t)(row0 + r) * 128 + t] = acc[r];
}

// ---------------- z2 = c0*base1 + c1*base2 + c2*(mm_in @ W)   (dual)
__global__ __launch_bounds__(128) void integ2_kernel(
    const float* __restrict__ mma, const float* __restrict__ Wa,
    const float* __restrict__ b1a, const float* __restrict__ b2a, float* __restrict__ oa,
    const float* __restrict__ mmb, const float* __restrict__ Wb,
    const float* __restrict__ b1b, const float* __restrict__ b2b, float* __restrict__ ob,
    const int blocksPer,
    const float* __restrict__ a1p, const float* __restrict__ a2p, const float* __restrict__ b2p)
{
    const float a1 = *a1p, a2 = *a2p, b2 = *b2p;
    const float c0 = 1.f - a2 - b2;
    const float c1 = a2 + b2 * (1.f - a1);
    const float c2 = b2 * a1;

    __shared__ float sIn[8][128];
    int bid = blockIdx.x;
    const float *mm_in, *W, *base1, *base2; float* outp;
    if (bid < blocksPer) { mm_in = mma; W = Wa; base1 = b1a; base2 = b2a; outp = oa; }
    else { bid -= blocksPer; mm_in = mmb; W = Wb; base1 = b1b; base2 = b2b; outp = ob; }

    const int row0 = bid * 8;
    const int t = threadIdx.x;
    for (int i = t; i < 8 * 128; i += 128) sIn[i >> 7][i & 127] = mm_in[(size_t)row0 * 128 + i];
    __syncthreads();
    float acc[8];
#pragma unroll
    for (int r = 0; r < 8; ++r) acc[r] = 0.f;
    for (int k = 0; k < 128; ++k) {
        const float wv = W[k * 128 + t];
#pragma unroll
        for (int r = 0; r < 8; ++r) acc[r] += sIn[r][k] * wv;
    }
#pragma unroll
    for (int r = 0; r < 8; ++r) {
        const size_t idx = (size_t)(row0 + r) * 128 + t;
        outp[idx] = c0 * base1[idx] + c1 * base2[idx] + c2 * acc[r];
    }
}

extern "C" void kernel_launch(void* const* d_in, const int* in_sizes, int n_in,
                              void* d_out, int out_size, void* d_ws, size_t ws_size,
                              hipStream_t stream)
{
    const int* x        = (const int*)d_in[0];
    const int* idx_sim0 = (const int*)d_in[1];
    const int* idx_cor0 = (const int*)d_in[2];
    const int* idx_sim1 = (const int*)d_in[3];
    const int* idx_cor1 = (const int*)d_in[4];
    const float* e0s  = (const float*)d_in[5];
    const float* e1s  = (const float*)d_in[6];
    const float* e2s  = (const float*)d_in[7];
    const float* Wins = (const float*)d_in[8];
    const float* bins = (const float*)d_in[9];
    const float* Wouts= (const float*)d_in[10];
    const float* bouts= (const float*)d_in[11];
    const float* e0c  = (const float*)d_in[12];
    const float* e1c  = (const float*)d_in[13];
    const float* e2c  = (const float*)d_in[14];
    const float* Winc = (const float*)d_in[15];
    const float* binc = (const float*)d_in[16];
    const float* Woutc= (const float*)d_in[17];
    const float* boutc= (const float*)d_in[18];
    const float* Ws2c = (const float*)d_in[19];
    const float* Wc2s = (const float*)d_in[20];
    const float* a1 = (const float*)d_in[21];
    const float* a2 = (const float*)d_in[22];
    const float* b2 = (const float*)d_in[23];

    float* outSim = (float*)d_out;
    float* outCor = outSim + 6000 * 128;

    float* ws = (float*)d_ws;
    const size_t needMerged = (size_t)(2 * 16000 * 256 + 2 * 12000 * 256 + 2 * 6000 * 256 + 4 * 6000 * 128) * 4;
    const bool merged = ws_size >= needMerged;

    if (merged) {
        float* A0 = ws;
        float* A1 = A0 + 16000 * 256;
        float* B0 = A1 + 16000 * 256;
        float* B1 = B0 + 12000 * 256;
        float* C0 = B1 + 12000 * 256;
        float* C1 = C0 + 6000 * 256;
        float* simO = C1 + 6000 * 256;
        float* corO = simO + 6000 * 128;
        float* P    = corO + 6000 * 128;
        float* S    = P + 6000 * 128;

        embed_fc_kernel<<<2000, 256, 0, stream>>>(x,
            e0s, e1s, e2s, Wins, bins, A0,
            e0c, e1c, e2c, Winc, binc, A1, 1000);
        // sim: D=feat[idx_cor], Q=feat[idx_sim]; cor: swapped
        coagg_kernel<10><<<6000, 256, 0, stream>>>(
            A0, idx_cor0, idx_sim0, B0,
            A1, idx_sim0, idx_cor0, B1, 12000, 1);
        coagg_kernel<5><<<3000, 256, 0, stream>>>(
            B0, idx_cor1, idx_sim1, C0,
            B1, idx_sim1, idx_cor1, C1, 6000, 0);
        fc_out_kernel<<<1500, 128, 0, stream>>>(
            C0, Wouts, bouts, simO,
            C1, Woutc, boutc, corO, 750);
        // P = cor@Wc2s ; S = sim@Ws2c
        mm128_kernel<<<1500, 128, 0, stream>>>(
            corO, Wc2s, P,
            simO, Ws2c, S, 750);
        // z2sim = c0*sim + c1*P + c2*(S@Wc2s) ; z2cor = c0*cor + c1*S + c2*(P@Ws2c)
        integ2_kernel<<<1500, 128, 0, stream>>>(
            S, Wc2s, simO, P, outSim,
            P, Ws2c, corO, S, outCor, 750, a1, a2, b2);
    } else {
        float* A = ws;
        float* B = A + 16000 * 256;
        float* C = B + 12000 * 256;
        float* simO = C + 6000 * 256;
        float* corO = simO + 6000 * 128;
        float* P    = corO + 6000 * 128;
        float* S    = P + 6000 * 128;

        for (int b = 0; b < 2; ++b) {
            const float* e0   = (b == 0) ? e0s : e0c;
            const float* e1   = (b == 0) ? e1s : e1c;
            const float* e2   = (b == 0) ? e2s : e2c;
            const float* Win  = (b == 0) ? Wins : Winc;
            const float* bin  = (b == 0) ? bins : binc;
            const float* Wout = (b == 0) ? Wouts : Woutc;
            const float* bout = (b == 0) ? bouts : boutc;
            const int* iD0 = (b == 0) ? idx_cor0 : idx_sim0;
            const int* iQ0 = (b == 0) ? idx_sim0 : idx_cor0;
            const int* iD1 = (b == 0) ? idx_cor1 : idx_sim1;
            const int* iQ1 = (b == 0) ? idx_sim1 : idx_cor1;
            float* branchOut = (b == 0) ? simO : corO;

            embed_fc_kernel<<<1000, 256, 0, stream>>>(x,
                e0, e1, e2, Win, bin, A,
                e0, e1, e2, Win, bin, A, 1000);
            coagg_kernel<10><<<3000, 256, 0, stream>>>(
                A, iD0, iQ0, B, A, iD0, iQ0, B, 12000, 1);
            coagg_kernel<5><<<1500, 256, 0, stream>>>(
                B, iD1, iQ1, C, B, iD1, iQ1, C, 6000, 0);
            fc_out_kernel<<<750, 128, 0, stream>>>(
                C, Wout, bout, branchOut,
                C, Wout, bout, branchOut, 750);
        }
        mm128_kernel<<<1500, 128, 0, stream>>>(
            corO, Wc2s, P,
            simO, Ws2c, S, 750);
        integ2_kernel<<<1500, 128, 0, stream>>>(
            S, Wc2s, simO, P, outSim,
            P, Ws2c, corO, S, outCor, 750, a1, a2, b2);
    }
}

// Round 8
// 203.597 us; speedup vs baseline: 1.0121x; 1.0121x over previous
//
#include <hip/hip_runtime.h>

#define CH 256

// DPP helper: v += dpp_move(v); bound_ctrl=true => out-of-range lanes read 0.
template <int CTRL>
__device__ __forceinline__ float dppAdd(float v) {
    const int m = __builtin_amdgcn_update_dpp(0, __builtin_bit_cast(int, v), CTRL, 0xf, 0xf, true);
    return v + __builtin_bit_cast(float, m);
}

// Opaque register pin: compiler can no longer rematerialize (reload) the value,
// so it MUST stay resident in VGPRs. Zero-cost no-op asm.
#define OPAQUE4(v) asm volatile("" : "+v"((v).x), "+v"((v).y), "+v"((v).z), "+v"((v).w))

// ---------------- embed + fc_input (dual-branch): 16 rows/block
__global__ __launch_bounds__(256) void embed_fc_kernel(
    const int* __restrict__ x,
    const float* __restrict__ e0a, const float* __restrict__ e1a, const float* __restrict__ e2a,
    const float* __restrict__ Wina, const float* __restrict__ bina, float* __restrict__ h0a,
    const float* __restrict__ e0b, const float* __restrict__ e1b, const float* __restrict__ e2b,
    const float* __restrict__ Winb, const float* __restrict__ binb, float* __restrict__ h0b,
    const int blocksPer)
{
    __shared__ float sE[16][128];
    int bid = blockIdx.x;
    const float *e0, *e1, *e2, *Win, *bin;
    float* h0;
    if (bid < blocksPer) { e0 = e0a; e1 = e1a; e2 = e2a; Win = Wina; bin = bina; h0 = h0a; }
    else { bid -= blocksPer; e0 = e0b; e1 = e1b; e2 = e2b; Win = Winb; bin = binb; h0 = h0b; }

    const int row0 = bid * 16;
    const int t = threadIdx.x;
    for (int i = t; i < 16 * 128; i += 256) {
        const int r = i >> 7, k = i & 127;
        const int row = row0 + r;
        float v;
        if (k < 64)      v = e0[x[row * 3 + 0] * 64 + k];
        else if (k < 96) v = e1[x[row * 3 + 1] * 32 + (k - 64)];
        else             v = e2[x[row * 3 + 2] * 32 + (k - 96)];
        sE[r][k] = v;
    }
    __syncthreads();
    const int j = t;
    float acc[16];
    const float b = bin[j];
#pragma unroll
    for (int r = 0; r < 16; ++r) acc[r] = b;
    for (int k = 0; k < 128; ++k) {
        const float wv = Win[k * 256 + j];
#pragma unroll
        for (int r = 0; r < 16; ++r) acc[r] += sE[r][k] * wv;
    }
#pragma unroll
    for (int r = 0; r < 16; ++r) h0[(size_t)(row0 + r) * 256 + j] = acc[r];
}

// ---------------- co-attention aggregation (dual-branch); ONE WAVE per dst node
// L[k][m]=<D[k],Q[m]>; AC=row-softmax; AS[c][m]=softmax_m L[m][c]
// sum_k h[k] = [ sum Q | sum_m w_m D_m | sum_j u_j Q_j ], w=colsum(AS), u=AC^T w
// 4 waves/block, no __syncthreads: per-wave LDS slices, intra-wave RAW ordered
// by program order + compiler lgkmcnt. D,Q pinned in registers via OPAQUE4
// (rounds 6/7: VGPR_Count=64 < 80 needed proved the allocator was reloading
// rows from global inside the L-phase -> ~3.1 GB L2 traffic = the bottleneck).
template <int K>
__global__ __launch_bounds__(256, 2) void coagg_kernel(
    const float* __restrict__ fa, const int* __restrict__ iDa, const int* __restrict__ iQa,
    float* __restrict__ oa,
    const float* __restrict__ fb, const int* __restrict__ iDb, const int* __restrict__ iQb,
    float* __restrict__ ob,
    const int nPer, const int relu)
{
    __shared__ float sL[4][K][K];
    __shared__ float sLT[4][K][K];          // transposed copy for the merged softmax pass
    __shared__ float sAC[4][K][K];
    __shared__ float sAS[4][K][K];
    __shared__ float sw_[4][K], su_[4][K];
    __shared__ __align__(16) float sHsum[4][768];

    const int t = threadIdx.x;
    const int wv = t >> 6, lane = t & 63;
    int n = blockIdx.x * 4 + wv;             // grid sized so 4 | total nodes

    const float* feat; const int* idxD; const int* idxQ; float* outp;
    if (n < nPer) { feat = fa; idxD = iDa; idxQ = iQa; outp = oa; }
    else { n -= nPer; feat = fb; idxD = iDb; idxQ = iQb; outp = ob; }

    const float4* fp = (const float4*)feat;

    // gather D,Q rows into registers (lane owns float4 feature slice)
    float4 d[K], q[K];
#pragma unroll
    for (int k = 0; k < K; ++k) {
        const int rD = idxD[n * K + k];
        const int rQ = idxQ[n * K + k];
        d[k] = fp[(size_t)rD * 64 + lane];
        q[k] = fp[(size_t)rQ * 64 + lane];
    }
    const float4 resid = fp[(size_t)n * 64 + lane];
    // pin gathered rows: forbids remat-by-reload (the round-6/7 L2 bottleneck)
#pragma unroll
    for (int k = 0; k < K; ++k) { OPAQUE4(d[k]); OPAQUE4(q[k]); }

    // L-phase: verified 2-pair permlane32_swap + DPP ladder (round 5).
    //   lane31 -> dot(m0), lane63 -> dot(m0+1); store L and L^T.
#pragma unroll
    for (int k = 0; k < K; ++k) {
        const float4 dd = d[k];
#pragma unroll
        for (int m0 = 0; m0 < K; m0 += 2) {
            const float4 q0 = q[m0];
            float s0 = dd.x * q0.x + dd.y * q0.y + dd.z * q0.z + dd.w * q0.w;
            float s1 = 0.f;
            if (m0 + 1 < K) {                 // compile-time after unroll
                const float4 q1 = q[m0 + 1];
                s1 = dd.x * q1.x + dd.y * q1.y + dd.z * q1.z + dd.w * q1.w;
            }
            asm volatile("v_permlane32_swap_b32 %0, %1" : "+v"(s0), "+v"(s1));
            float r = s0 + s1;
            r = dppAdd<0x111>(r);   // row_shr:1
            r = dppAdd<0x112>(r);   // row_shr:2
            r = dppAdd<0x114>(r);   // row_shr:4
            r = dppAdd<0x118>(r);   // row_shr:8
            r = dppAdd<0x142>(r);   // row_bcast:15
            if (lane == 31) { sL[wv][k][m0] = r; sLT[wv][m0][k] = r; }
            if (lane == 63 && m0 + 1 < K) { sL[wv][k][m0 + 1] = r; sLT[wv][m0 + 1][k] = r; }
        }
    }

    // stage A: both softmaxes in ONE exec pass.
    //   lanes 0..K-1   : AC row r from sL[r][:]   -> sAC[r][:]
    //   lanes 16..16+K-1: AS row r from sLT[r][:] -> sAS[r][:]
    {
        const int g = lane >> 4;              // group 0 = AC, 1 = AS
        const int r2 = lane & 15;
        if (g < 2 && r2 < K) {
            const float* Lrow = (g == 0) ? &sL[wv][r2][0] : &sLT[wv][r2][0];
            float* Arow       = (g == 0) ? &sAC[wv][r2][0] : &sAS[wv][r2][0];
            float e_[K], mx = -1e30f;
#pragma unroll
            for (int m = 0; m < K; ++m) mx = fmaxf(mx, Lrow[m]);
            float ssum = 0.f;
#pragma unroll
            for (int m = 0; m < K; ++m) { e_[m] = __expf(Lrow[m] - mx); ssum += e_[m]; }
            const float inv = 1.f / ssum;
#pragma unroll
            for (int m = 0; m < K; ++m) Arow[m] = e_[m] * inv;
        }
    }
    // stage B: w[m] = colsum(AS)   (lanes 32..32+K-1; reads stage-A writes)
    {
        const int m2 = lane - 32;
        if (m2 >= 0 && m2 < K) {
            float s = 0.f;
#pragma unroll
            for (int k2 = 0; k2 < K; ++k2) s += sAS[wv][k2][m2];
            sw_[wv][m2] = s;
        }
    }
    // stage C: u[j] = sum_m w[m]*AC[m][j]   (lanes 48..48+K-1)
    {
        const int j2 = lane - 48;
        if (j2 >= 0 && j2 < K) {
            float s = 0.f;
#pragma unroll
            for (int m = 0; m < K; ++m) s += sw_[wv][m] * sAC[wv][m][j2];
            su_[wv][j2] = s;
        }
    }

    // stage D: weighted row sums (all lanes; D,Q in regs; w,u broadcast reads)
    float4 h0v = make_float4(0.f, 0.f, 0.f, 0.f);
    float4 h1v = make_float4(0.f, 0.f, 0.f, 0.f);
    float4 h2v = make_float4(0.f, 0.f, 0.f, 0.f);
#pragma unroll
    for (int kx = 0; kx < K; ++kx) {
        const float wk = sw_[wv][kx];
        const float uk = su_[wv][kx];
        const float4 qq = q[kx];
        const float4 dd = d[kx];
        h0v.x += qq.x;      h0v.y += qq.y;      h0v.z += qq.z;      h0v.w += qq.w;
        h1v.x += wk * dd.x; h1v.y += wk * dd.y; h1v.z += wk * dd.z; h1v.w += wk * dd.w;
        h2v.x += uk * qq.x; h2v.y += uk * qq.y; h2v.z += uk * qq.z; h2v.w += uk * qq.w;
    }
    ((float4*)&sHsum[wv][0])[lane]       = h0v;
    ((float4*)&sHsum[wv][0])[64 + lane]  = h1v;
    ((float4*)&sHsum[wv][0])[128 + lane] = h2v;

    // stage E: pool3 + mean_k + residual (reads same-wave sHsum)
    float ov[4];
#pragma unroll
    for (int i = 0; i < 4; ++i) {
        const int f = lane * 4 + i;
        ov[i] = (sHsum[wv][3 * f] + sHsum[wv][3 * f + 1] + sHsum[wv][3 * f + 2])
                * (1.0f / (3.0f * K));
    }
    float4 o = make_float4(resid.x + ov[0], resid.y + ov[1],
                           resid.z + ov[2], resid.w + ov[3]);
    if (relu) {
        o.x = fmaxf(o.x, 0.f); o.y = fmaxf(o.y, 0.f);
        o.z = fmaxf(o.z, 0.f); o.w = fmaxf(o.w, 0.f);
    }
    ((float4*)outp)[(size_t)n * 64 + lane] = o;
}

// ---------------- h2[.x256] @ Wout[256x128] + bout (dual-branch)
__global__ __launch_bounds__(128) void fc_out_kernel(
    const float* __restrict__ h2a, const float* __restrict__ Wouta,
    const float* __restrict__ bouta, float* __restrict__ oa,
    const float* __restrict__ h2b, const float* __restrict__ Woutb,
    const float* __restrict__ boutb, float* __restrict__ ob,
    const int blocksPer)
{
    __shared__ float sIn[8][256];
    int bid = blockIdx.x;
    const float *h2, *Wout, *bout; float* outp;
    if (bid < blocksPer) { h2 = h2a; Wout = Wouta; bout = bouta; outp = oa; }
    else { bid -= blocksPer; h2 = h2b; Wout = Woutb; bout = boutb; outp = ob; }

    const int row0 = bid * 8;
    const int t = threadIdx.x;
    for (int i = t; i < 8 * 256; i += 128) sIn[i >> 8][i & 255] = h2[(size_t)row0 * 256 + i];
    __syncthreads();
    float acc[8];
    const float b = bout[t];
#pragma unroll
    for (int r = 0; r < 8; ++r) acc[r] = b;
    for (int k = 0; k < 256; ++k) {
        const float wv = Wout[k * 128 + t];
#pragma unroll
        for (int r = 0; r < 8; ++r) acc[r] += sIn[r][k] * wv;
    }
#pragma unroll
    for (int r = 0; r < 8; ++r) outp[(size_t)(row0 + r) * 128 + t] = acc[r];
}

// ---------------- out = in[.x128] @ W[128x128] (dual)
__global__ __launch_bounds__(128) void mm128_kernel(
    const float* __restrict__ ina, const float* __restrict__ Wa, float* __restrict__ oa,
    const float* __restrict__ inb, const float* __restrict__ Wb, float* __restrict__ ob,
    const int blocksPer)
{
    __shared__ float sIn[8][128];
    int bid = blockIdx.x;
    const float *inp, *W; float* outp;
    if (bid < blocksPer) { inp = ina; W = Wa; outp = oa; }
    else { bid -= blocksPer; inp = inb; W = Wb; outp = ob; }

    const int row0 = bid * 8;
    const int t = threadIdx.x;
    for (int i = t; i < 8 * 128; i += 128) sIn[i >> 7][i & 127] = inp[(size_t)row0 * 128 + i];
    __syncthreads();
    float acc[8];
#pragma unroll
    for (int r = 0; r < 8; ++r) acc[r] = 0.f;
    for (int k = 0; k < 128; ++k) {
        const float wv = W[k * 128 + t];
#pragma unroll
        for (int r = 0; r < 8; ++r) acc[r] += sIn[r][k] * wv;
    }
#pragma unroll
    for (int r = 0; r < 8; ++r) outp[(size_t)(row0 + r) * 128 + t] = acc[r];
}

// ---------------- z2 = c0*base1 + c1*base2 + c2*(mm_in @ W)   (dual)
__global__ __launch_bounds__(128) void integ2_kernel(
    const float* __restrict__ mma, const float* __restrict__ Wa,
    const float* __restrict__ b1a, const float* __restrict__ b2a, float* __restrict__ oa,
    const float* __restrict__ mmb, const float* __restrict__ Wb,
    const float* __restrict__ b1b, const float* __restrict__ b2b, float* __restrict__ ob,
    const int blocksPer,
    const float* __restrict__ a1p, const float* __restrict__ a2p, const float* __restrict__ b2p)
{
    const float a1 = *a1p, a2 = *a2p, b2 = *b2p;
    const float c0 = 1.f - a2 - b2;
    const float c1 = a2 + b2 * (1.f - a1);
    const float c2 = b2 * a1;

    __shared__ float sIn[8][128];
    int bid = blockIdx.x;
    const float *mm_in, *W, *base1, *base2; float* outp;
    if (bid < blocksPer) { mm_in = mma; W = Wa; base1 = b1a; base2 = b2a; outp = oa; }
    else { bid -= blocksPer; mm_in = mmb; W = Wb; base1 = b1b; base2 = b2b; outp = ob; }

    const int row0 = bid * 8;
    const int t = threadIdx.x;
    for (int i = t; i < 8 * 128; i += 128) sIn[i >> 7][i & 127] = mm_in[(size_t)row0 * 128 + i];
    __syncthreads();
    float acc[8];
#pragma unroll
    for (int r = 0; r < 8; ++r) acc[r] = 0.f;
    for (int k = 0; k < 128; ++k) {
        const float wv = W[k * 128 + t];
#pragma unroll
        for (int r = 0; r < 8; ++r) acc[r] += sIn[r][k] * wv;
    }
#pragma unroll
    for (int r = 0; r < 8; ++r) {
        const size_t idx = (size_t)(row0 + r) * 128 + t;
        outp[idx] = c0 * base1[idx] + c1 * base2[idx] + c2 * acc[r];
    }
}

extern "C" void kernel_launch(void* const* d_in, const int* in_sizes, int n_in,
                              void* d_out, int out_size, void* d_ws, size_t ws_size,
                              hipStream_t stream)
{
    const int* x        = (const int*)d_in[0];
    const int* idx_sim0 = (const int*)d_in[1];
    const int* idx_cor0 = (const int*)d_in[2];
    const int* idx_sim1 = (const int*)d_in[3];
    const int* idx_cor1 = (const int*)d_in[4];
    const float* e0s  = (const float*)d_in[5];
    const float* e1s  = (const float*)d_in[6];
    const float* e2s  = (const float*)d_in[7];
    const float* Wins = (const float*)d_in[8];
    const float* bins = (const float*)d_in[9];
    const float* Wouts= (const float*)d_in[10];
    const float* bouts= (const float*)d_in[11];
    const float* e0c  = (const float*)d_in[12];
    const float* e1c  = (const float*)d_in[13];
    const float* e2c  = (const float*)d_in[14];
    const float* Winc = (const float*)d_in[15];
    const float* binc = (const float*)d_in[16];
    const float* Woutc= (const float*)d_in[17];
    const float* boutc= (const float*)d_in[18];
    const float* Ws2c = (const float*)d_in[19];
    const float* Wc2s = (const float*)d_in[20];
    const float* a1 = (const float*)d_in[21];
    const float* a2 = (const float*)d_in[22];
    const float* b2 = (const float*)d_in[23];

    float* outSim = (float*)d_out;
    float* outCor = outSim + 6000 * 128;

    float* ws = (float*)d_ws;
    const size_t needMerged = (size_t)(2 * 16000 * 256 + 2 * 12000 * 256 + 2 * 6000 * 256 + 4 * 6000 * 128) * 4;
    const bool merged = ws_size >= needMerged;

    if (merged) {
        float* A0 = ws;
        float* A1 = A0 + 16000 * 256;
        float* B0 = A1 + 16000 * 256;
        float* B1 = B0 + 12000 * 256;
        float* C0 = B1 + 12000 * 256;
        float* C1 = C0 + 6000 * 256;
        float* simO = C1 + 6000 * 256;
        float* corO = simO + 6000 * 128;
        float* P    = corO + 6000 * 128;
        float* S    = P + 6000 * 128;

        embed_fc_kernel<<<2000, 256, 0, stream>>>(x,
            e0s, e1s, e2s, Wins, bins, A0,
            e0c, e1c, e2c, Winc, binc, A1, 1000);
        // sim: D=feat[idx_cor], Q=feat[idx_sim]; cor: swapped
        coagg_kernel<10><<<6000, 256, 0, stream>>>(
            A0, idx_cor0, idx_sim0, B0,
            A1, idx_sim0, idx_cor0, B1, 12000, 1);
        coagg_kernel<5><<<3000, 256, 0, stream>>>(
            B0, idx_cor1, idx_sim1, C0,
            B1, idx_sim1, idx_cor1, C1, 6000, 0);
        fc_out_kernel<<<1500, 128, 0, stream>>>(
            C0, Wouts, bouts, simO,
            C1, Woutc, boutc, corO, 750);
        // P = cor@Wc2s ; S = sim@Ws2c
        mm128_kernel<<<1500, 128, 0, stream>>>(
            corO, Wc2s, P,
            simO, Ws2c, S, 750);
        // z2sim = c0*sim + c1*P + c2*(S@Wc2s) ; z2cor = c0*cor + c1*S + c2*(P@Ws2c)
        integ2_kernel<<<1500, 128, 0, stream>>>(
            S, Wc2s, simO, P, outSim,
            P, Ws2c, corO, S, outCor, 750, a1, a2, b2);
    } else {
        float* A = ws;
        float* B = A + 16000 * 256;
        float* C = B + 12000 * 256;
        float* simO = C + 6000 * 256;
        float* corO = simO + 6000 * 128;
        float* P    = corO + 6000 * 128;
        float* S    = P + 6000 * 128;

        for (int b = 0; b < 2; ++b) {
            const float* e0   = (b == 0) ? e0s : e0c;
            const float* e1   = (b == 0) ? e1s : e1c;
            const float* e2   = (b == 0) ? e2s : e2c;
            const float* Win  = (b == 0) ? Wins : Winc;
            const float* bin  = (b == 0) ? bins : binc;
            const float* Wout = (b == 0) ? Wouts : Woutc;
            const float* bout = (b == 0) ? bouts : boutc;
            const int* iD0 = (b == 0) ? idx_cor0 : idx_sim0;
            const int* iQ0 = (b == 0) ? idx_sim0 : idx_cor0;
            const int* iD1 = (b == 0) ? idx_cor1 : idx_sim1;
            const int* iQ1 = (b == 0) ? idx_sim1 : idx_cor1;
            float* branchOut = (b == 0) ? simO : corO;

            embed_fc_kernel<<<1000, 256, 0, stream>>>(x,
                e0, e1, e2, Win, bin, A,
                e0, e1, e2, Win, bin, A, 1000);
            coagg_kernel<10><<<3000, 256, 0, stream>>>(
                A, iD0, iQ0, B, A, iD0, iQ0, B, 12000, 1);
            coagg_kernel<5><<<1500, 256, 0, stream>>>(
                B, iD1, iQ1, C, B, iD1, iQ1, C, 6000, 0);
            fc_out_kernel<<<750, 128, 0, stream>>>(
                C, Wout, bout, branchOut,
                C, Wout, bout, branchOut, 750);
        }
        mm128_kernel<<<1500, 128, 0, stream>>>(
            corO, Wc2s, P,
            simO, Ws2c, S, 750);
        integ2_kernel<<<1500, 128, 0, stream>>>(
            S, Wc2s, simO, P, outSim,
            P, Ws2c, corO, S, outCor, 750, a1, a2, b2);
    }
}

// Round 9
// 182.498 us; speedup vs baseline: 1.1291x; 1.1156x over previous
//
#include <hip/hip_runtime.h>

#define CH 256

// DPP helper: v += dpp_move(v); bound_ctrl=true => out-of-range lanes read 0.
template <int CTRL>
__device__ __forceinline__ float dppAdd(float v) {
    const int m = __builtin_amdgcn_update_dpp(0, __builtin_bit_cast(int, v), CTRL, 0xf, 0xf, true);
    return v + __builtin_bit_cast(float, m);
}

#define OPAQUE4(v) asm volatile("" : "+v"((v).x), "+v"((v).y), "+v"((v).z), "+v"((v).w))

// ---------------- embed + fc_input v2: register-tiled GEMM, 32 rows/block
// eT staging: (r,kc) pairs, r=lane&31, kc=2w+(lane>>5)+8j  (bijective)
__global__ __launch_bounds__(256) void embed_fc2_kernel(
    const int* __restrict__ x,
    const float* __restrict__ e0a, const float* __restrict__ e1a, const float* __restrict__ e2a,
    const float* __restrict__ Wina, const float* __restrict__ bina, float* __restrict__ h0a,
    const float* __restrict__ e0b, const float* __restrict__ e1b, const float* __restrict__ e2b,
    const float* __restrict__ Winb, const float* __restrict__ binb, float* __restrict__ h0b,
    const int blocksPer)
{
    __shared__ __align__(16) float eT[128][32];   // transposed embed tile
    int bid = blockIdx.x;
    const float *e0, *e1, *e2, *Win, *bin;
    float* h0;
    if (bid < blocksPer) { e0 = e0a; e1 = e1a; e2 = e2a; Win = Wina; bin = bina; h0 = h0a; }
    else { bid -= blocksPer; e0 = e0b; e1 = e1b; e2 = e2b; Win = Winb; bin = binb; h0 = h0b; }

    const int row0 = bid * 32;
    const int t = threadIdx.x;
    const int w = t >> 6, l = t & 63;
    const int r = l & 31;
    const int kcBase = 2 * w + (l >> 5);

    // stage: each (r,kc) loads e[row][4kc..4kc+4) and writes transposed
#pragma unroll
    for (int j = 0; j < 4; ++j) {
        const int kc = kcBase + 8 * j;
        const int k0 = kc * 4;
        const int row = row0 + r;
        float4 v;
        if (kc < 16)      v = *(const float4*)(e0 + (size_t)x[row * 3 + 0] * 64 + k0);
        else if (kc < 24) v = *(const float4*)(e1 + (size_t)x[row * 3 + 1] * 32 + (k0 - 64));
        else              v = *(const float4*)(e2 + (size_t)x[row * 3 + 2] * 32 + (k0 - 96));
        eT[k0 + 0][r] = v.x; eT[k0 + 1][r] = v.y; eT[k0 + 2][r] = v.z; eT[k0 + 3][r] = v.w;
    }
    __syncthreads();

    // compute: wave w owns rows w*8..w*8+8; lane l owns cols l*4..l*4+4
    const float4 bb = *(const float4*)(bin + l * 4);
    float acc[8][4];
#pragma unroll
    for (int rr = 0; rr < 8; ++rr) {
        acc[rr][0] = bb.x; acc[rr][1] = bb.y; acc[rr][2] = bb.z; acc[rr][3] = bb.w;
    }
#pragma unroll 4
    for (int k = 0; k < 128; ++k) {
        const float4 wv = *(const float4*)(Win + (size_t)k * 256 + l * 4);
        const float4 ea = *(const float4*)&eT[k][w * 8];
        const float4 eb = *(const float4*)&eT[k][w * 8 + 4];
        const float ev[8] = {ea.x, ea.y, ea.z, ea.w, eb.x, eb.y, eb.z, eb.w};
#pragma unroll
        for (int rr = 0; rr < 8; ++rr) {
            acc[rr][0] += ev[rr] * wv.x; acc[rr][1] += ev[rr] * wv.y;
            acc[rr][2] += ev[rr] * wv.z; acc[rr][3] += ev[rr] * wv.w;
        }
    }
#pragma unroll
    for (int rr = 0; rr < 8; ++rr) {
        float4 o = make_float4(acc[rr][0], acc[rr][1], acc[rr][2], acc[rr][3]);
        *(float4*)(h0 + (size_t)(row0 + w * 8 + rr) * 256 + l * 4) = o;
    }
}

// ---------------- generic 32-row register-tiled GEMM, Cout=128
// MODE 0: out = in@W + bias(aux)      (fc_out)
// MODE 1: out = c0*aux + c1*aux2 + c2*(in@W)   (integ2)
// MODE 2: out = in@W                  (mm128)
template <int KD, int MODE>
__global__ __launch_bounds__(256) void gemm32_kernel(
    const float* __restrict__ ina, const float* __restrict__ Wa,
    const float* __restrict__ auxa, const float* __restrict__ aux2a, float* __restrict__ oa,
    const float* __restrict__ inb, const float* __restrict__ Wb,
    const float* __restrict__ auxb, const float* __restrict__ aux2b, float* __restrict__ ob,
    const int blocksPer, const int nRows,
    const float* __restrict__ a1p, const float* __restrict__ a2p, const float* __restrict__ b2p)
{
    __shared__ __align__(16) float inT[KD][32];
    int bid = blockIdx.x;
    const float *in, *W, *aux, *aux2; float* outp;
    if (bid < blocksPer) { in = ina; W = Wa; aux = auxa; aux2 = aux2a; outp = oa; }
    else { bid -= blocksPer; in = inb; W = Wb; aux = auxb; aux2 = aux2b; outp = ob; }

    const int row0 = bid * 32;
    const int t = threadIdx.x;
    const int w = t >> 6, l = t & 63;
    const int r = l & 31;
    const int kcBase = 2 * w + (l >> 5);

    // stage transposed (row-clamped; stores guarded later)
#pragma unroll
    for (int j = 0; j < KD / 32; ++j) {
        const int kc = kcBase + 8 * j;
        const int k0 = kc * 4;
        int row = row0 + r;
        if (row >= nRows) row = nRows - 1;
        const float4 v = *(const float4*)(in + (size_t)row * KD + k0);
        inT[k0 + 0][r] = v.x; inT[k0 + 1][r] = v.y; inT[k0 + 2][r] = v.z; inT[k0 + 3][r] = v.w;
    }
    __syncthreads();

    // compute: rg = w*2 + (l>>5) -> rows rg*4..rg*4+4; cols (l&31)*4..+4
    const int rg = w * 2 + (l >> 5);
    const int r0 = rg * 4;
    const int cc0 = (l & 31) * 4;

    float acc[4][4];
    if constexpr (MODE == 0) {
        const float4 bb = *(const float4*)(aux + cc0);   // bias
#pragma unroll
        for (int rr = 0; rr < 4; ++rr) {
            acc[rr][0] = bb.x; acc[rr][1] = bb.y; acc[rr][2] = bb.z; acc[rr][3] = bb.w;
        }
    } else {
#pragma unroll
        for (int rr = 0; rr < 4; ++rr) acc[rr][0] = acc[rr][1] = acc[rr][2] = acc[rr][3] = 0.f;
    }

#pragma unroll 4
    for (int k = 0; k < KD; ++k) {
        const float4 wv = *(const float4*)(W + (size_t)k * 128 + cc0);
        const float4 ea = *(const float4*)&inT[k][r0];
        const float ev[4] = {ea.x, ea.y, ea.z, ea.w};
#pragma unroll
        for (int rr = 0; rr < 4; ++rr) {
            acc[rr][0] += ev[rr] * wv.x; acc[rr][1] += ev[rr] * wv.y;
            acc[rr][2] += ev[rr] * wv.z; acc[rr][3] += ev[rr] * wv.w;
        }
    }

    float c0 = 0.f, c1 = 0.f, c2 = 0.f;
    if constexpr (MODE == 1) {
        const float a1 = *a1p, a2 = *a2p, b2 = *b2p;
        c0 = 1.f - a2 - b2;
        c1 = a2 + b2 * (1.f - a1);
        c2 = b2 * a1;
    }

#pragma unroll
    for (int rr = 0; rr < 4; ++rr) {
        const int row = row0 + r0 + rr;
        if (row < nRows) {
            float4 o = make_float4(acc[rr][0], acc[rr][1], acc[rr][2], acc[rr][3]);
            if constexpr (MODE == 1) {
                const size_t idx = (size_t)row * 128 + cc0;
                const float4 b1v = *(const float4*)(aux + idx);
                const float4 b2v = *(const float4*)(aux2 + idx);
                o.x = c0 * b1v.x + c1 * b2v.x + c2 * o.x;
                o.y = c0 * b1v.y + c1 * b2v.y + c2 * o.y;
                o.z = c0 * b1v.z + c1 * b2v.z + c2 * o.z;
                o.w = c0 * b1v.w + c1 * b2v.w + c2 * o.w;
            }
            *(float4*)(outp + (size_t)row * 128 + cc0) = o;
        }
    }
}

// ---------------- co-attention aggregation (FROZEN from round 8)
template <int K>
__global__ __launch_bounds__(256, 2) void coagg_kernel(
    const float* __restrict__ fa, const int* __restrict__ iDa, const int* __restrict__ iQa,
    float* __restrict__ oa,
    const float* __restrict__ fb, const int* __restrict__ iDb, const int* __restrict__ iQb,
    float* __restrict__ ob,
    const int nPer, const int relu)
{
    __shared__ float sL[4][K][K];
    __shared__ float sLT[4][K][K];
    __shared__ float sAC[4][K][K];
    __shared__ float sAS[4][K][K];
    __shared__ float sw_[4][K], su_[4][K];
    __shared__ __align__(16) float sHsum[4][768];

    const int t = threadIdx.x;
    const int wv = t >> 6, lane = t & 63;
    int n = blockIdx.x * 4 + wv;

    const float* feat; const int* idxD; const int* idxQ; float* outp;
    if (n < nPer) { feat = fa; idxD = iDa; idxQ = iQa; outp = oa; }
    else { n -= nPer; feat = fb; idxD = iDb; idxQ = iQb; outp = ob; }

    const float4* fp = (const float4*)feat;

    float4 d[K], q[K];
#pragma unroll
    for (int k = 0; k < K; ++k) {
        const int rD = idxD[n * K + k];
        const int rQ = idxQ[n * K + k];
        d[k] = fp[(size_t)rD * 64 + lane];
        q[k] = fp[(size_t)rQ * 64 + lane];
    }
    const float4 resid = fp[(size_t)n * 64 + lane];
#pragma unroll
    for (int k = 0; k < K; ++k) { OPAQUE4(d[k]); OPAQUE4(q[k]); }

#pragma unroll
    for (int k = 0; k < K; ++k) {
        const float4 dd = d[k];
#pragma unroll
        for (int m0 = 0; m0 < K; m0 += 2) {
            const float4 q0 = q[m0];
            float s0 = dd.x * q0.x + dd.y * q0.y + dd.z * q0.z + dd.w * q0.w;
            float s1 = 0.f;
            if (m0 + 1 < K) {
                const float4 q1 = q[m0 + 1];
                s1 = dd.x * q1.x + dd.y * q1.y + dd.z * q1.z + dd.w * q1.w;
            }
            asm volatile("v_permlane32_swap_b32 %0, %1" : "+v"(s0), "+v"(s1));
            float r = s0 + s1;
            r = dppAdd<0x111>(r);
            r = dppAdd<0x112>(r);
            r = dppAdd<0x114>(r);
            r = dppAdd<0x118>(r);
            r = dppAdd<0x142>(r);
            if (lane == 31) { sL[wv][k][m0] = r; sLT[wv][m0][k] = r; }
            if (lane == 63 && m0 + 1 < K) { sL[wv][k][m0 + 1] = r; sLT[wv][m0 + 1][k] = r; }
        }
    }

    {
        const int g = lane >> 4;
        const int r2 = lane & 15;
        if (g < 2 && r2 < K) {
            const float* Lrow = (g == 0) ? &sL[wv][r2][0] : &sLT[wv][r2][0];
            float* Arow       = (g == 0) ? &sAC[wv][r2][0] : &sAS[wv][r2][0];
            float e_[K], mx = -1e30f;
#pragma unroll
            for (int m = 0; m < K; ++m) mx = fmaxf(mx, Lrow[m]);
            float ssum = 0.f;
#pragma unroll
            for (int m = 0; m < K; ++m) { e_[m] = __expf(Lrow[m] - mx); ssum += e_[m]; }
            const float inv = 1.f / ssum;
#pragma unroll
            for (int m = 0; m < K; ++m) Arow[m] = e_[m] * inv;
        }
    }
    {
        const int m2 = lane - 32;
        if (m2 >= 0 && m2 < K) {
            float s = 0.f;
#pragma unroll
            for (int k2 = 0; k2 < K; ++k2) s += sAS[wv][k2][m2];
            sw_[wv][m2] = s;
        }
    }
    {
        const int j2 = lane - 48;
        if (j2 >= 0 && j2 < K) {
            float s = 0.f;
#pragma unroll
            for (int m = 0; m < K; ++m) s += sw_[wv][m] * sAC[wv][m][j2];
            su_[wv][j2] = s;
        }
    }

    float4 h0v = make_float4(0.f, 0.f, 0.f, 0.f);
    float4 h1v = make_float4(0.f, 0.f, 0.f, 0.f);
    float4 h2v = make_float4(0.f, 0.f, 0.f, 0.f);
#pragma unroll
    for (int kx = 0; kx < K; ++kx) {
        const float wk = sw_[wv][kx];
        const float uk = su_[wv][kx];
        const float4 qq = q[kx];
        const float4 dd = d[kx];
        h0v.x += qq.x;      h0v.y += qq.y;      h0v.z += qq.z;      h0v.w += qq.w;
        h1v.x += wk * dd.x; h1v.y += wk * dd.y; h1v.z += wk * dd.z; h1v.w += wk * dd.w;
        h2v.x += uk * qq.x; h2v.y += uk * qq.y; h2v.z += uk * qq.z; h2v.w += uk * qq.w;
    }
    ((float4*)&sHsum[wv][0])[lane]       = h0v;
    ((float4*)&sHsum[wv][0])[64 + lane]  = h1v;
    ((float4*)&sHsum[wv][0])[128 + lane] = h2v;

    float ov[4];
#pragma unroll
    for (int i = 0; i < 4; ++i) {
        const int f = lane * 4 + i;
        ov[i] = (sHsum[wv][3 * f] + sHsum[wv][3 * f + 1] + sHsum[wv][3 * f + 2])
                * (1.0f / (3.0f * K));
    }
    float4 o = make_float4(resid.x + ov[0], resid.y + ov[1],
                           resid.z + ov[2], resid.w + ov[3]);
    if (relu) {
        o.x = fmaxf(o.x, 0.f); o.y = fmaxf(o.y, 0.f);
        o.z = fmaxf(o.z, 0.f); o.w = fmaxf(o.w, 0.f);
    }
    ((float4*)outp)[(size_t)n * 64 + lane] = o;
}

extern "C" void kernel_launch(void* const* d_in, const int* in_sizes, int n_in,
                              void* d_out, int out_size, void* d_ws, size_t ws_size,
                              hipStream_t stream)
{
    const int* x        = (const int*)d_in[0];
    const int* idx_sim0 = (const int*)d_in[1];
    const int* idx_cor0 = (const int*)d_in[2];
    const int* idx_sim1 = (const int*)d_in[3];
    const int* idx_cor1 = (const int*)d_in[4];
    const float* e0s  = (const float*)d_in[5];
    const float* e1s  = (const float*)d_in[6];
    const float* e2s  = (const float*)d_in[7];
    const float* Wins = (const float*)d_in[8];
    const float* bins = (const float*)d_in[9];
    const float* Wouts= (const float*)d_in[10];
    const float* bouts= (const float*)d_in[11];
    const float* e0c  = (const float*)d_in[12];
    const float* e1c  = (const float*)d_in[13];
    const float* e2c  = (const float*)d_in[14];
    const float* Winc = (const float*)d_in[15];
    const float* binc = (const float*)d_in[16];
    const float* Woutc= (const float*)d_in[17];
    const float* boutc= (const float*)d_in[18];
    const float* Ws2c = (const float*)d_in[19];
    const float* Wc2s = (const float*)d_in[20];
    const float* a1 = (const float*)d_in[21];
    const float* a2 = (const float*)d_in[22];
    const float* b2 = (const float*)d_in[23];

    float* outSim = (float*)d_out;
    float* outCor = outSim + 6000 * 128;

    float* ws = (float*)d_ws;
    const size_t needMerged = (size_t)(2 * 16000 * 256 + 2 * 12000 * 256 + 2 * 6000 * 256 + 4 * 6000 * 128) * 4;
    const bool merged = ws_size >= needMerged;

    const int fcBlocks = (6000 + 31) / 32;   // 188

    if (merged) {
        float* A0 = ws;
        float* A1 = A0 + 16000 * 256;
        float* B0 = A1 + 16000 * 256;
        float* B1 = B0 + 12000 * 256;
        float* C0 = B1 + 12000 * 256;
        float* C1 = C0 + 6000 * 256;
        float* simO = C1 + 6000 * 256;
        float* corO = simO + 6000 * 128;
        float* P    = corO + 6000 * 128;
        float* S    = P + 6000 * 128;

        embed_fc2_kernel<<<1000, 256, 0, stream>>>(x,
            e0s, e1s, e2s, Wins, bins, A0,
            e0c, e1c, e2c, Winc, binc, A1, 500);
        // sim: D=feat[idx_cor], Q=feat[idx_sim]; cor: swapped
        coagg_kernel<10><<<6000, 256, 0, stream>>>(
            A0, idx_cor0, idx_sim0, B0,
            A1, idx_sim0, idx_cor0, B1, 12000, 1);
        coagg_kernel<5><<<3000, 256, 0, stream>>>(
            B0, idx_cor1, idx_sim1, C0,
            B1, idx_sim1, idx_cor1, C1, 6000, 0);
        gemm32_kernel<256, 0><<<2 * fcBlocks, 256, 0, stream>>>(
            C0, Wouts, bouts, nullptr, simO,
            C1, Woutc, boutc, nullptr, corO, fcBlocks, 6000, a1, a2, b2);
        // P = cor@Wc2s ; S = sim@Ws2c
        gemm32_kernel<128, 2><<<2 * fcBlocks, 256, 0, stream>>>(
            corO, Wc2s, nullptr, nullptr, P,
            simO, Ws2c, nullptr, nullptr, S, fcBlocks, 6000, a1, a2, b2);
        // z2sim = c0*sim + c1*P + c2*(S@Wc2s) ; z2cor = c0*cor + c1*S + c2*(P@Ws2c)
        gemm32_kernel<128, 1><<<2 * fcBlocks, 256, 0, stream>>>(
            S, Wc2s, simO, P, outSim,
            P, Ws2c, corO, S, outCor, fcBlocks, 6000, a1, a2, b2);
    } else {
        float* A = ws;
        float* B = A + 16000 * 256;
        float* C = B + 12000 * 256;
        float* simO = C + 6000 * 256;
        float* corO = simO + 6000 * 128;
        float* P    = corO + 6000 * 128;
        float* S    = P + 6000 * 128;

        for (int b = 0; b < 2; ++b) {
            const float* e0   = (b == 0) ? e0s : e0c;
            const float* e1   = (b == 0) ? e1s : e1c;
            const float* e2   = (b == 0) ? e2s : e2c;
            const float* Win  = (b == 0) ? Wins : Winc;
            const float* bin  = (b == 0) ? bins : binc;
            const float* Wout = (b == 0) ? Wouts : Woutc;
            const float* bout = (b == 0) ? bouts : boutc;
            const int* iD0 = (b == 0) ? idx_cor0 : idx_sim0;
            const int* iQ0 = (b == 0) ? idx_sim0 : idx_cor0;
            const int* iD1 = (b == 0) ? idx_cor1 : idx_sim1;
            const int* iQ1 = (b == 0) ? idx_sim1 : idx_cor1;
            float* branchOut = (b == 0) ? simO : corO;

            embed_fc2_kernel<<<500, 256, 0, stream>>>(x,
                e0, e1, e2, Win, bin, A,
                e0, e1, e2, Win, bin, A, 500);
            coagg_kernel<10><<<3000, 256, 0, stream>>>(
                A, iD0, iQ0, B, A, iD0, iQ0, B, 12000, 1);
            coagg_kernel<5><<<1500, 256, 0, stream>>>(
                B, iD1, iQ1, C, B, iD1, iQ1, C, 6000, 0);
            gemm32_kernel<256, 0><<<fcBlocks, 256, 0, stream>>>(
                C, Wout, bout, nullptr, branchOut,
                C, Wout, bout, nullptr, branchOut, fcBlocks, 6000, a1, a2, b2);
        }
        gemm32_kernel<128, 2><<<2 * fcBlocks, 256, 0, stream>>>(
            corO, Wc2s, nullptr, nullptr, P,
            simO, Ws2c, nullptr, nullptr, S, fcBlocks, 6000, a1, a2, b2);
        gemm32_kernel<128, 1><<<2 * fcBlocks, 256, 0, stream>>>(
            S, Wc2s, simO, P, outSim,
            P, Ws2c, corO, S, outCor, fcBlocks, 6000, a1, a2, b2);
    }
}